// Round 1
// baseline (378.742 us; speedup 1.0000x reference)
//
#include <hip/hip_runtime.h>

using u16 = unsigned short;

typedef float  f32x4  __attribute__((ext_vector_type(4)));
typedef __bf16 bf16x8 __attribute__((ext_vector_type(8)));
typedef short  s16x8  __attribute__((ext_vector_type(8)));

#define DEVI __device__ __forceinline__

constexpr int TOK = 8192;    // N = B*L
constexpr int CIN = 1024;    // C
constexpr int C3  = 3072;    // 3C
constexpr int NH  = 16;
constexpr int HD  = 64;
constexpr int SL  = 2048;
constexpr int BH  = 64;      // B*H

constexpr float LOG2E = 1.4426950408889634f;

DEVI u16 f2bf(float x) {
  unsigned u = __builtin_bit_cast(unsigned, x);
  u += 0x7FFFu + ((u >> 16) & 1u);   // round-to-nearest-even
  return (u16)(u >> 16);
}

DEVI f32x4 mfma16(s16x8 a, s16x8 b, f32x4 c) {
  return __builtin_amdgcn_mfma_f32_16x16x32_bf16(
      __builtin_bit_cast(bf16x8, a), __builtin_bit_cast(bf16x8, b), c, 0, 0, 0);
}

DEVI void gload_lds16(const void* g, void* l) {
  __builtin_amdgcn_global_load_lds(
      (const __attribute__((address_space(1))) unsigned int*)g,
      (__attribute__((address_space(3))) unsigned int*)l, 16, 0, 0);
}

// ---------------- convert x (fp32) -> bf16 ----------------
__global__ __launch_bounds__(256) void k_cvt_x(const float* __restrict__ x,
                                               u16* __restrict__ xb) {
  const int total = TOK * CIN / 4;
  for (int i = blockIdx.x * 256 + threadIdx.x; i < total; i += gridDim.x * 256) {
    float4 v = ((const float4*)x)[i];
    ushort4 o;
    o.x = f2bf(v.x); o.y = f2bf(v.y); o.z = f2bf(v.z); o.w = f2bf(v.w);
    ((ushort4*)xb)[i] = o;
  }
}

// ---------------- transpose fp32 [R][C] -> bf16 [C][R] ----------------
__global__ __launch_bounds__(256) void k_transpose(const float* __restrict__ in,
                                                   u16* __restrict__ out,
                                                   int R, int C) {
  __shared__ u16 t[64][72];
  int rt = R >> 6;
  int tr = (blockIdx.x % rt) << 6;
  int tc = (blockIdx.x / rt) << 6;
  int tid = threadIdx.x;
#pragma unroll
  for (int k2 = 0; k2 < 16; k2++) {
    int idx = k2 * 256 + tid;
    int r = idx >> 6, c = idx & 63;
    t[r][c] = f2bf(in[(size_t)(tr + r) * C + tc + c]);
  }
  __syncthreads();
#pragma unroll
  for (int k2 = 0; k2 < 16; k2++) {
    int idx = k2 * 256 + tid;
    int r = idx >> 6, c = idx & 63;
    out[(size_t)(tc + r) * R + tr + c] = t[c][r];
  }
}

// ---------------- GEMM1: qkv = xb @ wqkvT^T, fused bias+norm+repack ----------------
// A: [8192][1024] bf16, Bt: [3072][1024] bf16
__global__ __launch_bounds__(256) void k_gemm_qkv(
    const u16* __restrict__ A, const u16* __restrict__ Bt,
    const float* __restrict__ bias, const float* __restrict__ gq,
    const float* __restrict__ gk,
    u16* __restrict__ Qn, u16* __restrict__ Kn, u16* __restrict__ Vt) {
  constexpr int BK = 32, K = 1024, NT = C3 / 128;
  __shared__ u16 As[128 * BK], Bs[128 * BK];
  const int bm = (blockIdx.x / NT) * 128, bn = (blockIdx.x % NT) * 128;
  const int tid = threadIdx.x, lane = tid & 63, w = tid >> 6;
  const int l15 = lane & 15, g = lane >> 4;
  const int wr = (w >> 1) * 64, wc = (w & 1) * 64;

  f32x4 acc[4][4];
#pragma unroll
  for (int i = 0; i < 4; i++)
#pragma unroll
    for (int j = 0; j < 4; j++) acc[i][j] = f32x4{0.f, 0.f, 0.f, 0.f};

  const int srow = tid >> 2, scol = (tid & 3) * 8;
  const u16* Ag = A + (size_t)(bm + srow) * K + scol;
  const u16* Bg = Bt + (size_t)(bn + srow) * K + scol;
  char* AsB = (char*)As;
  char* BsB = (char*)Bs;

  for (int k0 = 0; k0 < K; k0 += BK) {
    __syncthreads();
    gload_lds16(Ag + k0,          AsB + w * 1024);
    gload_lds16(Ag + 64 * K + k0, AsB + 4096 + w * 1024);
    gload_lds16(Bg + k0,          BsB + w * 1024);
    gload_lds16(Bg + 64 * K + k0, BsB + 4096 + w * 1024);
    __syncthreads();
    s16x8 af[4], bf[4];
#pragma unroll
    for (int mf = 0; mf < 4; mf++)
      af[mf] = *(const s16x8*)(As + (wr + mf * 16 + l15) * BK + g * 8);
#pragma unroll
    for (int nf = 0; nf < 4; nf++)
      bf[nf] = *(const s16x8*)(Bs + (wc + nf * 16 + l15) * BK + g * 8);
#pragma unroll
    for (int mf = 0; mf < 4; mf++)
#pragma unroll
      for (int nf = 0; nf < 4; nf++)
        acc[mf][nf] = mfma16(af[mf], bf[nf], acc[mf][nf]);
  }

  // epilogue: bias, per-head L2 norm for q/k (64 cols == one head), repack
  const int c0 = bn + wc;             // 64-aligned
  const int sec = c0 >> 10;           // 0=q 1=k 2=v
  const int head = (c0 & 1023) >> 6;
  float bv[4], gv[4];
#pragma unroll
  for (int nf = 0; nf < 4; nf++) {
    bv[nf] = bias[c0 + nf * 16 + l15];
    gv[nf] = 1.f;
    if (sec == 0) gv[nf] = gq[head * 64 + nf * 16 + l15];
    if (sec == 1) gv[nf] = gk[head * 64 + nf * 16 + l15];
  }
#pragma unroll
  for (int mf = 0; mf < 4; mf++) {
#pragma unroll
    for (int nf = 0; nf < 4; nf++)
#pragma unroll
      for (int r = 0; r < 4; r++) acc[mf][nf][r] += bv[nf];
    if (sec < 2) {
#pragma unroll
      for (int r = 0; r < 4; r++) {
        float ss = 0.f;
#pragma unroll
        for (int nf = 0; nf < 4; nf++) ss += acc[mf][nf][r] * acc[mf][nf][r];
        ss += __shfl_xor(ss, 1); ss += __shfl_xor(ss, 2);
        ss += __shfl_xor(ss, 4); ss += __shfl_xor(ss, 8);
        float nrm = fmaxf(sqrtf(ss), 1e-12f);
        float f = (sec == 0 ? LOG2E : 8.0f) / nrm;
#pragma unroll
        for (int nf = 0; nf < 4; nf++) acc[mf][nf][r] *= f;
      }
    }
    int rbase = bm + wr + mf * 16 + 4 * g;
#pragma unroll
    for (int r = 0; r < 4; r++) {
      int row = rbase + r;
      int b = row >> 11, tok = row & 2047;
      int bh = b * NH + head;
#pragma unroll
      for (int nf = 0; nf < 4; nf++) {
        int d = nf * 16 + l15;
        u16 val = f2bf(acc[mf][nf][r] * gv[nf]);
        if (sec == 0)      Qn[((size_t)bh * SL + tok) * HD + d] = val;
        else if (sec == 1) Kn[((size_t)bh * SL + tok) * HD + d] = val;
        else               Vt[((size_t)bh * HD + d) * SL + tok] = val;
      }
    }
  }
}

// ---------------- flash attention ----------------
__global__ __launch_bounds__(256) void k_attn(const u16* __restrict__ Qn,
                                              const u16* __restrict__ Kn,
                                              const u16* __restrict__ Vt,
                                              u16* __restrict__ hm) {
  __shared__ u16 P[4][32 * 72];
  const int bh = blockIdx.x & 63, qb = blockIdx.x >> 6;
  const int tid = threadIdx.x, lane = tid & 63, w = tid >> 6;
  const int l15 = lane & 15, g = lane >> 4;
  const int qr0 = qb * 128 + w * 32;
  const u16* Qb = Qn + (size_t)bh * SL * HD;
  const u16* Kb = Kn + (size_t)bh * SL * HD;
  const u16* Vb = Vt + (size_t)bh * HD * SL;

  s16x8 qf[2][2];
#pragma unroll
  for (int mf = 0; mf < 2; mf++)
#pragma unroll
    for (int kf = 0; kf < 2; kf++)
      qf[mf][kf] = *(const s16x8*)(Qb + (qr0 + mf * 16 + l15) * HD + kf * 32 + g * 8);

  f32x4 o[2][4];
  float mr[2][4], lr[2][4];
#pragma unroll
  for (int mf = 0; mf < 2; mf++)
#pragma unroll
    for (int nf = 0; nf < 4; nf++) o[mf][nf] = f32x4{0.f, 0.f, 0.f, 0.f};
#pragma unroll
  for (int mf = 0; mf < 2; mf++)
#pragma unroll
    for (int r = 0; r < 4; r++) { mr[mf][r] = -1e30f; lr[mf][r] = 0.f; }

  u16* Pw = P[w];

  for (int kb = 0; kb < SL; kb += 64) {
    s16x8 kfr[4][2], vfr[4][2];
#pragma unroll
    for (int nf = 0; nf < 4; nf++)
#pragma unroll
      for (int kf = 0; kf < 2; kf++) {
        kfr[nf][kf] = *(const s16x8*)(Kb + (kb + nf * 16 + l15) * HD + kf * 32 + g * 8);
        vfr[nf][kf] = *(const s16x8*)(Vb + (nf * 16 + l15) * SL + kb + kf * 32 + g * 8);
      }
    f32x4 s[2][4];
#pragma unroll
    for (int mf = 0; mf < 2; mf++)
#pragma unroll
      for (int nf = 0; nf < 4; nf++) {
        f32x4 a = f32x4{0.f, 0.f, 0.f, 0.f};
        a = mfma16(qf[mf][0], kfr[nf][0], a);
        a = mfma16(qf[mf][1], kfr[nf][1], a);
        s[mf][nf] = a;
      }
    // online softmax (exp2 domain; log2e folded into Qn)
#pragma unroll
    for (int mf = 0; mf < 2; mf++)
#pragma unroll
      for (int r = 0; r < 4; r++) {
        float bm2 = fmaxf(fmaxf(s[mf][0][r], s[mf][1][r]),
                          fmaxf(s[mf][2][r], s[mf][3][r]));
        bm2 = fmaxf(bm2, __shfl_xor(bm2, 1));
        bm2 = fmaxf(bm2, __shfl_xor(bm2, 2));
        bm2 = fmaxf(bm2, __shfl_xor(bm2, 4));
        bm2 = fmaxf(bm2, __shfl_xor(bm2, 8));
        float mn = fmaxf(mr[mf][r], bm2);
        float sc = __builtin_amdgcn_exp2f(mr[mf][r] - mn);
        mr[mf][r] = mn;
        float rs = 0.f;
#pragma unroll
        for (int nf = 0; nf < 4; nf++) {
          float p = __builtin_amdgcn_exp2f(s[mf][nf][r] - mn);
          s[mf][nf][r] = p;
          rs += p;
        }
        rs += __shfl_xor(rs, 1); rs += __shfl_xor(rs, 2);
        rs += __shfl_xor(rs, 4); rs += __shfl_xor(rs, 8);
        lr[mf][r] = lr[mf][r] * sc + rs;
#pragma unroll
        for (int nf = 0; nf < 4; nf++) o[mf][nf][r] *= sc;
      }
    // P -> LDS (C-layout write), re-read as A-fragments
#pragma unroll
    for (int mf = 0; mf < 2; mf++)
#pragma unroll
      for (int nf = 0; nf < 4; nf++)
#pragma unroll
        for (int r = 0; r < 4; r++)
          Pw[(mf * 16 + 4 * g + r) * 72 + nf * 16 + l15] = f2bf(s[mf][nf][r]);
    asm volatile("s_waitcnt lgkmcnt(0)" ::: "memory");
    s16x8 pa[2][2];
#pragma unroll
    for (int mf = 0; mf < 2; mf++)
#pragma unroll
      for (int kf = 0; kf < 2; kf++)
        pa[mf][kf] = *(const s16x8*)(Pw + (mf * 16 + l15) * 72 + kf * 32 + g * 8);
#pragma unroll
    for (int mf = 0; mf < 2; mf++)
#pragma unroll
      for (int nf = 0; nf < 4; nf++) {
        o[mf][nf] = mfma16(pa[mf][0], vfr[nf][0], o[mf][nf]);
        o[mf][nf] = mfma16(pa[mf][1], vfr[nf][1], o[mf][nf]);
      }
  }
  // epilogue: normalize by l, store bf16 h
  const int b = bh >> 4, hh = bh & 15;
#pragma unroll
  for (int mf = 0; mf < 2; mf++)
#pragma unroll
    for (int r = 0; r < 4; r++) {
      float inv = 1.f / lr[mf][r];
      int tok = qr0 + mf * 16 + 4 * g + r;
#pragma unroll
      for (int nf = 0; nf < 4; nf++) {
        float v = o[mf][nf][r] * inv;
        hm[((size_t)b * SL + tok) * CIN + hh * 64 + nf * 16 + l15] = f2bf(v);
      }
    }
}

// ---------------- GEMM2: out = hm @ woutT^T + b_out (fp32 out) ----------------
__global__ __launch_bounds__(256) void k_gemm_out(
    const u16* __restrict__ A, const u16* __restrict__ Bt,
    const float* __restrict__ bias, float* __restrict__ out) {
  constexpr int BK = 32, K = 1024, NT = CIN / 128;
  __shared__ u16 As[128 * BK], Bs[128 * BK];
  const int bm = (blockIdx.x / NT) * 128, bn = (blockIdx.x % NT) * 128;
  const int tid = threadIdx.x, lane = tid & 63, w = tid >> 6;
  const int l15 = lane & 15, g = lane >> 4;
  const int wr = (w >> 1) * 64, wc = (w & 1) * 64;

  f32x4 acc[4][4];
#pragma unroll
  for (int i = 0; i < 4; i++)
#pragma unroll
    for (int j = 0; j < 4; j++) acc[i][j] = f32x4{0.f, 0.f, 0.f, 0.f};

  const int srow = tid >> 2, scol = (tid & 3) * 8;
  const u16* Ag = A + (size_t)(bm + srow) * K + scol;
  const u16* Bg = Bt + (size_t)(bn + srow) * K + scol;
  char* AsB = (char*)As;
  char* BsB = (char*)Bs;

  for (int k0 = 0; k0 < K; k0 += BK) {
    __syncthreads();
    gload_lds16(Ag + k0,          AsB + w * 1024);
    gload_lds16(Ag + 64 * K + k0, AsB + 4096 + w * 1024);
    gload_lds16(Bg + k0,          BsB + w * 1024);
    gload_lds16(Bg + 64 * K + k0, BsB + 4096 + w * 1024);
    __syncthreads();
    s16x8 af[4], bf[4];
#pragma unroll
    for (int mf = 0; mf < 4; mf++)
      af[mf] = *(const s16x8*)(As + (wr + mf * 16 + l15) * BK + g * 8);
#pragma unroll
    for (int nf = 0; nf < 4; nf++)
      bf[nf] = *(const s16x8*)(Bs + (wc + nf * 16 + l15) * BK + g * 8);
#pragma unroll
    for (int mf = 0; mf < 4; mf++)
#pragma unroll
      for (int nf = 0; nf < 4; nf++)
        acc[mf][nf] = mfma16(af[mf], bf[nf], acc[mf][nf]);
  }

  float bv[4];
#pragma unroll
  for (int nf = 0; nf < 4; nf++) bv[nf] = bias[bn + wc + nf * 16 + l15];
#pragma unroll
  for (int mf = 0; mf < 4; mf++)
#pragma unroll
    for (int r = 0; r < 4; r++) {
      int row = bm + wr + mf * 16 + 4 * g + r;
#pragma unroll
      for (int nf = 0; nf < 4; nf++)
        out[(size_t)row * CIN + bn + wc + nf * 16 + l15] = acc[mf][nf][r] + bv[nf];
    }
}

extern "C" void kernel_launch(void* const* d_in, const int* in_sizes, int n_in,
                              void* d_out, int out_size, void* d_ws, size_t ws_size,
                              hipStream_t stream) {
  const float* x    = (const float*)d_in[0];
  const float* Wqkv = (const float*)d_in[1];
  const float* bqkv = (const float*)d_in[2];
  const float* gq   = (const float*)d_in[3];
  const float* gk   = (const float*)d_in[4];
  const float* Wout = (const float*)d_in[5];
  const float* bout = (const float*)d_in[6];
  float* out = (float*)d_out;

  char* ws = (char*)d_ws;
  u16* xb  = (u16*)(ws);                       // 16,777,216 B
  u16* wqT = (u16*)(ws + 16777216);            //  6,291,456 B
  u16* woT = (u16*)(ws + 23068672);            //  2,097,152 B
  u16* Qn  = (u16*)(ws + 25165824);            // 16,777,216 B
  u16* Kn  = (u16*)(ws + 41943040);            // 16,777,216 B
  u16* Vt  = (u16*)(ws + 58720256);            // 16,777,216 B
  u16* hm  = (u16*)(ws + 75497472);            // 16,777,216 B  (end: 92,274,688)

  k_cvt_x<<<2048, 256, 0, stream>>>(x, xb);
  k_transpose<<<(1024 / 64) * (3072 / 64), 256, 0, stream>>>(Wqkv, wqT, 1024, 3072);
  k_transpose<<<(1024 / 64) * (1024 / 64), 256, 0, stream>>>(Wout, woT, 1024, 1024);
  k_gemm_qkv<<<(TOK / 128) * (C3 / 128), 256, 0, stream>>>(xb, wqT, bqkv, gq, gk, Qn, Kn, Vt);
  k_attn<<<BH * (SL / 128), 256, 0, stream>>>(Qn, Kn, Vt, hm);
  k_gemm_out<<<(TOK / 128) * (CIN / 128), 256, 0, stream>>>(hm, woT, bout, out);
}

// Round 2
// 255.920 us; speedup vs baseline: 1.4799x; 1.4799x over previous
//
#include <hip/hip_runtime.h>

using u16 = unsigned short;

typedef float  f32x4  __attribute__((ext_vector_type(4)));
typedef float  f32x16 __attribute__((ext_vector_type(16)));
typedef __bf16 bf16x8 __attribute__((ext_vector_type(8)));
typedef short  s16x8  __attribute__((ext_vector_type(8)));

#define DEVI __device__ __forceinline__

constexpr int TOK = 8192;    // N = B*L
constexpr int CIN = 1024;    // C
constexpr int C3  = 3072;    // 3C
constexpr int NH  = 16;
constexpr int HD  = 64;
constexpr int SL  = 2048;
constexpr int BH  = 64;      // B*H

constexpr float LOG2E = 1.4426950408889634f;

DEVI u16 f2bf(float x) {
  unsigned u = __builtin_bit_cast(unsigned, x);
  u += 0x7FFFu + ((u >> 16) & 1u);   // round-to-nearest-even
  return (u16)(u >> 16);
}

DEVI f32x4 mfma16(s16x8 a, s16x8 b, f32x4 c) {
  return __builtin_amdgcn_mfma_f32_16x16x32_bf16(
      __builtin_bit_cast(bf16x8, a), __builtin_bit_cast(bf16x8, b), c, 0, 0, 0);
}

DEVI f32x16 mfma32(s16x8 a, s16x8 b, f32x16 c) {
  return __builtin_amdgcn_mfma_f32_32x32x16_bf16(
      __builtin_bit_cast(bf16x8, a), __builtin_bit_cast(bf16x8, b), c, 0, 0, 0);
}

DEVI void gload_lds16(const void* g, void* l) {
  __builtin_amdgcn_global_load_lds(
      (const __attribute__((address_space(1))) unsigned int*)g,
      (__attribute__((address_space(3))) unsigned int*)l, 16, 0, 0);
}

DEVI unsigned cvtpk(float lo, float hi) {
  unsigned r;
  asm("v_cvt_pk_bf16_f32 %0, %1, %2" : "=v"(r) : "v"(lo), "v"(hi));
  return r;
}

DEVI void plswap(unsigned& a, unsigned& b) {
  asm("v_permlane32_swap_b32 %0, %1" : "+v"(a), "+v"(b));
}

// ---------------- convert x (fp32) -> bf16 ----------------
__global__ __launch_bounds__(256) void k_cvt_x(const float* __restrict__ x,
                                               u16* __restrict__ xb) {
  const int total = TOK * CIN / 4;
  for (int i = blockIdx.x * 256 + threadIdx.x; i < total; i += gridDim.x * 256) {
    float4 v = ((const float4*)x)[i];
    ushort4 o;
    o.x = f2bf(v.x); o.y = f2bf(v.y); o.z = f2bf(v.z); o.w = f2bf(v.w);
    ((ushort4*)xb)[i] = o;
  }
}

// ---------------- transpose fp32 [R][C] -> bf16 [C][R] ----------------
__global__ __launch_bounds__(256) void k_transpose(const float* __restrict__ in,
                                                   u16* __restrict__ out,
                                                   int R, int C) {
  __shared__ u16 t[64][72];
  int rt = R >> 6;
  int tr = (blockIdx.x % rt) << 6;
  int tc = (blockIdx.x / rt) << 6;
  int tid = threadIdx.x;
#pragma unroll
  for (int k2 = 0; k2 < 16; k2++) {
    int idx = k2 * 256 + tid;
    int r = idx >> 6, c = idx & 63;
    t[r][c] = f2bf(in[(size_t)(tr + r) * C + tc + c]);
  }
  __syncthreads();
#pragma unroll
  for (int k2 = 0; k2 < 16; k2++) {
    int idx = k2 * 256 + tid;
    int r = idx >> 6, c = idx & 63;
    out[(size_t)(tc + r) * R + tr + c] = t[c][r];
  }
}

// ---------------- GEMM1: qkv = xb @ wqkvT^T, fused bias+norm+repack ----------------
__global__ __launch_bounds__(256) void k_gemm_qkv(
    const u16* __restrict__ A, const u16* __restrict__ Bt,
    const float* __restrict__ bias, const float* __restrict__ gq,
    const float* __restrict__ gk,
    u16* __restrict__ Qn, u16* __restrict__ Kn, u16* __restrict__ Vt) {
  constexpr int BK = 32, K = 1024, NT = C3 / 128;
  __shared__ u16 As[128 * BK], Bs[128 * BK];
  const int bm = (blockIdx.x / NT) * 128, bn = (blockIdx.x % NT) * 128;
  const int tid = threadIdx.x, lane = tid & 63, w = tid >> 6;
  const int l15 = lane & 15, g = lane >> 4;
  const int wr = (w >> 1) * 64, wc = (w & 1) * 64;

  f32x4 acc[4][4];
#pragma unroll
  for (int i = 0; i < 4; i++)
#pragma unroll
    for (int j = 0; j < 4; j++) acc[i][j] = f32x4{0.f, 0.f, 0.f, 0.f};

  const int srow = tid >> 2, scol = (tid & 3) * 8;
  const u16* Ag = A + (size_t)(bm + srow) * K + scol;
  const u16* Bg = Bt + (size_t)(bn + srow) * K + scol;
  char* AsB = (char*)As;
  char* BsB = (char*)Bs;

  for (int k0 = 0; k0 < K; k0 += BK) {
    __syncthreads();
    gload_lds16(Ag + k0,          AsB + w * 1024);
    gload_lds16(Ag + 64 * K + k0, AsB + 4096 + w * 1024);
    gload_lds16(Bg + k0,          BsB + w * 1024);
    gload_lds16(Bg + 64 * K + k0, BsB + 4096 + w * 1024);
    __syncthreads();
    s16x8 af[4], bf[4];
#pragma unroll
    for (int mf = 0; mf < 4; mf++)
      af[mf] = *(const s16x8*)(As + (wr + mf * 16 + l15) * BK + g * 8);
#pragma unroll
    for (int nf = 0; nf < 4; nf++)
      bf[nf] = *(const s16x8*)(Bs + (wc + nf * 16 + l15) * BK + g * 8);
#pragma unroll
    for (int mf = 0; mf < 4; mf++)
#pragma unroll
      for (int nf = 0; nf < 4; nf++)
        acc[mf][nf] = mfma16(af[mf], bf[nf], acc[mf][nf]);
  }

  // epilogue: bias, per-head L2 norm for q/k (64 cols == one head), repack
  const int c0 = bn + wc;             // 64-aligned
  const int sec = c0 >> 10;           // 0=q 1=k 2=v
  const int head = (c0 & 1023) >> 6;
  float bv[4], gv[4];
#pragma unroll
  for (int nf = 0; nf < 4; nf++) {
    bv[nf] = bias[c0 + nf * 16 + l15];
    gv[nf] = 1.f;
    if (sec == 0) gv[nf] = gq[head * 64 + nf * 16 + l15];
    if (sec == 1) gv[nf] = gk[head * 64 + nf * 16 + l15];
  }
#pragma unroll
  for (int mf = 0; mf < 4; mf++) {
#pragma unroll
    for (int nf = 0; nf < 4; nf++)
#pragma unroll
      for (int r = 0; r < 4; r++) acc[mf][nf][r] += bv[nf];
    if (sec < 2) {
#pragma unroll
      for (int r = 0; r < 4; r++) {
        float ss = 0.f;
#pragma unroll
        for (int nf = 0; nf < 4; nf++) ss += acc[mf][nf][r] * acc[mf][nf][r];
        ss += __shfl_xor(ss, 1); ss += __shfl_xor(ss, 2);
        ss += __shfl_xor(ss, 4); ss += __shfl_xor(ss, 8);
        float nrm = fmaxf(sqrtf(ss), 1e-12f);
        float f = (sec == 0 ? LOG2E : 8.0f) / nrm;
#pragma unroll
        for (int nf = 0; nf < 4; nf++) acc[mf][nf][r] *= f;
      }
    }
    int rbase = bm + wr + mf * 16 + 4 * g;
#pragma unroll
    for (int r = 0; r < 4; r++) {
      int row = rbase + r;
      int b = row >> 11, tok = row & 2047;
      int bh = b * NH + head;
#pragma unroll
      for (int nf = 0; nf < 4; nf++) {
        int d = nf * 16 + l15;
        u16 val = f2bf(acc[mf][nf][r] * gv[nf]);
        if (sec == 0)      Qn[((size_t)bh * SL + tok) * HD + d] = val;
        else if (sec == 1) Kn[((size_t)bh * SL + tok) * HD + d] = val;
        else               Vt[((size_t)bh * HD + d) * SL + tok] = val;
      }
    }
  }
}

// ---------------- flash attention: 32x32 swapped QK^T, LDS-staged K/V ----------------
// Per block: 4 waves x 32 q-rows = 128 q. KVBLK=64, double-buffered K/V in LDS
// with XOR-swizzled layout (pre-swizzled global source, rule #21).
__global__ __launch_bounds__(256) void k_attn(const u16* __restrict__ Qn,
                                              const u16* __restrict__ Kn,
                                              const u16* __restrict__ Vt,
                                              u16* __restrict__ hm) {
  __shared__ __align__(16) char KL[2][8192];
  __shared__ __align__(16) char VL[2][8192];
  const int bh = blockIdx.x & 63, qb = blockIdx.x >> 6;
  const int tid = threadIdx.x, w = tid >> 6, lane = tid & 63;
  const int l31 = lane & 31, h = lane >> 5;
  const int qr0 = qb * 128 + w * 32;

  // ---- staging source addresses (per thread), pre-swizzled (T2 + m173) ----
  const int sr  = tid >> 3;                                  // 0..31 rows
  const int scb = ((tid & 7) << 4) ^ ((sr & 7) << 4);        // swizzled col-byte
  const char* kst = (const char*)(Kn + (size_t)bh * SL * HD) + (size_t)sr * 128 + scb;
  const char* vst = (const char*)(Vt + (size_t)bh * HD * SL) + (size_t)sr * 4096 + scb;
  char* kl0 = KL[0] + (w << 10);
  char* vl0 = VL[0] + (w << 10);
  char* kl1 = KL[1] + (w << 10);
  char* vl1 = VL[1] + (w << 10);

  // ---- Q B-fragments (once): lane holds Q[qr0+l31][ks*16 + 8h + j] ----
  const u16* Qb = Qn + ((size_t)bh * SL + qr0 + l31) * HD + 8 * h;
  s16x8 qf[4];
#pragma unroll
  for (int ks = 0; ks < 4; ks++) qf[ks] = *(const s16x8*)(Qb + ks * 16);

  // lane LDS read base byte offset (within a 32-row half tile)
  const int lb = l31 * 128 + ((h << 4) ^ ((l31 & 7) << 4));

  f32x16 o0, o1;
#pragma unroll
  for (int i = 0; i < 16; i++) { o0[i] = 0.f; o1[i] = 0.f; }
  float mr = -1e30f, lr = 0.f;

  // prologue: stage kb=0 into buf 0
  gload_lds16(kst,             kl0);
  gload_lds16(kst + 4096,      kl0 + 4096);
  gload_lds16(vst,             vl0);
  gload_lds16(vst + 32 * 4096, vl0 + 4096);
  __syncthreads();

  for (int it = 0; it < 32; ++it) {
    const char* KB = (it & 1) ? KL[1] : KL[0];
    const char* VB = (it & 1) ? VL[1] : VL[0];
    if (it < 31) {                                   // prefetch next tile
      const size_t ko = (size_t)(it + 1) << 13;      // 64 rows * 128 B
      const size_t vo = (size_t)(it + 1) << 7;       // 64 toks * 2 B
      char* kd = (it & 1) ? kl0 : kl1;
      char* vd = (it & 1) ? vl0 : vl1;
      gload_lds16(kst + ko,                kd);
      gload_lds16(kst + ko + 4096,         kd + 4096);
      gload_lds16(vst + vo,                vd);
      gload_lds16(vst + vo + 32 * 4096,    vd + 4096);
    }

    // ---- QK^T (swapped): S^T[k][q], lane = one q column ----
    f32x16 s0, s1;
#pragma unroll
    for (int i = 0; i < 16; i++) { s0[i] = 0.f; s1[i] = 0.f; }
#pragma unroll
    for (int ks = 0; ks < 4; ks++) {
      const s16x8 ka = *(const s16x8*)(KB + (lb ^ (ks << 5)));
      const s16x8 kb2 = *(const s16x8*)(KB + 4096 + (lb ^ (ks << 5)));
      s0 = mfma32(ka, qf[ks], s0);
      s1 = mfma32(kb2, qf[ks], s1);
    }

    // ---- online softmax: all 32 scores of this lane belong to q=l31 ----
    float ma = -1e30f, mb = -1e30f, mc = -1e30f, md = -1e30f;
#pragma unroll
    for (int i = 0; i < 4; i++) {
      ma = fmaxf(ma, fmaxf(s0[i], s0[i + 4]));
      mb = fmaxf(mb, fmaxf(s0[i + 8], s0[i + 12]));
      mc = fmaxf(mc, fmaxf(s1[i], s1[i + 4]));
      md = fmaxf(md, fmaxf(s1[i + 8], s1[i + 12]));
    }
    float bm = fmaxf(fmaxf(ma, mb), fmaxf(mc, md));
    bm = fmaxf(bm, __shfl_xor(bm, 32));
    const float mn = fmaxf(mr, bm);
    const float sc = __builtin_amdgcn_exp2f(mr - mn);
    mr = mn;
    float r0 = 0.f, r1 = 0.f;
#pragma unroll
    for (int i = 0; i < 16; i++) { s0[i] = __builtin_amdgcn_exp2f(s0[i] - mn); r0 += s0[i]; }
#pragma unroll
    for (int i = 0; i < 16; i++) { s1[i] = __builtin_amdgcn_exp2f(s1[i] - mn); r1 += s1[i]; }
    float rs = r0 + r1;
    rs += __shfl_xor(rs, 32);
    lr = lr * sc + rs;
#pragma unroll
    for (int i = 0; i < 16; i++) { o0[i] *= sc; o1[i] *= sc; }

    // ---- P -> bf16 B-fragments (T12: cvt_pk + permlane32_swap), PV ----
    union PBu { unsigned u[4]; s16x8 v; } pb;
#define MK_PB(SV, B)                              \
    {                                             \
      unsigned a0 = cvtpk(SV[B + 0], SV[B + 1]);  \
      unsigned c0 = cvtpk(SV[B + 4], SV[B + 5]);  \
      plswap(a0, c0);                             \
      unsigned a1 = cvtpk(SV[B + 2], SV[B + 3]);  \
      unsigned c1 = cvtpk(SV[B + 6], SV[B + 7]);  \
      plswap(a1, c1);                             \
      pb.u[0] = a0; pb.u[1] = a1; pb.u[2] = c0; pb.u[3] = c1; \
    }
#define PV_STEP(KS)                                            \
    {                                                          \
      const s16x8 va = *(const s16x8*)(VB + (lb ^ (KS << 5))); \
      const s16x8 vb = *(const s16x8*)(VB + 4096 + (lb ^ (KS << 5))); \
      o0 = mfma32(va, pb.v, o0);                               \
      o1 = mfma32(vb, pb.v, o1);                               \
    }
    MK_PB(s0, 0) PV_STEP(0)
    MK_PB(s0, 8) PV_STEP(1)
    MK_PB(s1, 0) PV_STEP(2)
    MK_PB(s1, 8) PV_STEP(3)
#undef MK_PB
#undef PV_STEP

    __syncthreads();   // drains vmcnt: next buffer staged; this buffer free
  }

  // ---- epilogue: O^T[d][q] / lr -> hm[b][tok][hh*64+d] ----
  const float inv = 1.f / lr;
  const int bq = bh >> 4, hh = bh & 15;
  u16* hb = hm + ((size_t)bq * SL + qr0 + l31) * CIN + hh * HD;
#pragma unroll
  for (int rg = 0; rg < 4; rg++) {
    const int d0 = 8 * rg + 4 * h;
    unsigned lo = cvtpk(o0[4 * rg + 0] * inv, o0[4 * rg + 1] * inv);
    unsigned hi = cvtpk(o0[4 * rg + 2] * inv, o0[4 * rg + 3] * inv);
    *(unsigned long long*)(hb + d0) =
        (unsigned long long)lo | ((unsigned long long)hi << 32);
    unsigned lo1 = cvtpk(o1[4 * rg + 0] * inv, o1[4 * rg + 1] * inv);
    unsigned hi1 = cvtpk(o1[4 * rg + 2] * inv, o1[4 * rg + 3] * inv);
    *(unsigned long long*)(hb + 32 + d0) =
        (unsigned long long)lo1 | ((unsigned long long)hi1 << 32);
  }
}

// ---------------- GEMM2: out = hm @ woutT^T + b_out (fp32 out) ----------------
__global__ __launch_bounds__(256) void k_gemm_out(
    const u16* __restrict__ A, const u16* __restrict__ Bt,
    const float* __restrict__ bias, float* __restrict__ out) {
  constexpr int BK = 32, K = 1024, NT = CIN / 128;
  __shared__ u16 As[128 * BK], Bs[128 * BK];
  const int bm = (blockIdx.x / NT) * 128, bn = (blockIdx.x % NT) * 128;
  const int tid = threadIdx.x, lane = tid & 63, w = tid >> 6;
  const int l15 = lane & 15, g = lane >> 4;
  const int wr = (w >> 1) * 64, wc = (w & 1) * 64;

  f32x4 acc[4][4];
#pragma unroll
  for (int i = 0; i < 4; i++)
#pragma unroll
    for (int j = 0; j < 4; j++) acc[i][j] = f32x4{0.f, 0.f, 0.f, 0.f};

  const int srow = tid >> 2, scol = (tid & 3) * 8;
  const u16* Ag = A + (size_t)(bm + srow) * K + scol;
  const u16* Bg = Bt + (size_t)(bn + srow) * K + scol;
  char* AsB = (char*)As;
  char* BsB = (char*)Bs;

  for (int k0 = 0; k0 < K; k0 += BK) {
    __syncthreads();
    gload_lds16(Ag + k0,          AsB + w * 1024);
    gload_lds16(Ag + 64 * K + k0, AsB + 4096 + w * 1024);
    gload_lds16(Bg + k0,          BsB + w * 1024);
    gload_lds16(Bg + 64 * K + k0, BsB + 4096 + w * 1024);
    __syncthreads();
    s16x8 af[4], bf[4];
#pragma unroll
    for (int mf = 0; mf < 4; mf++)
      af[mf] = *(const s16x8*)(As + (wr + mf * 16 + l15) * BK + g * 8);
#pragma unroll
    for (int nf = 0; nf < 4; nf++)
      bf[nf] = *(const s16x8*)(Bs + (wc + nf * 16 + l15) * BK + g * 8);
#pragma unroll
    for (int mf = 0; mf < 4; mf++)
#pragma unroll
      for (int nf = 0; nf < 4; nf++)
        acc[mf][nf] = mfma16(af[mf], bf[nf], acc[mf][nf]);
  }

  float bv[4];
#pragma unroll
  for (int nf = 0; nf < 4; nf++) bv[nf] = bias[bn + wc + nf * 16 + l15];
#pragma unroll
  for (int mf = 0; mf < 4; mf++)
#pragma unroll
    for (int r = 0; r < 4; r++) {
      int row = bm + wr + mf * 16 + 4 * g + r;
#pragma unroll
      for (int nf = 0; nf < 4; nf++)
        out[(size_t)row * CIN + bn + wc + nf * 16 + l15] = acc[mf][nf][r] + bv[nf];
    }
}

extern "C" void kernel_launch(void* const* d_in, const int* in_sizes, int n_in,
                              void* d_out, int out_size, void* d_ws, size_t ws_size,
                              hipStream_t stream) {
  const float* x    = (const float*)d_in[0];
  const float* Wqkv = (const float*)d_in[1];
  const float* bqkv = (const float*)d_in[2];
  const float* gq   = (const float*)d_in[3];
  const float* gk   = (const float*)d_in[4];
  const float* Wout = (const float*)d_in[5];
  const float* bout = (const float*)d_in[6];
  float* out = (float*)d_out;

  char* ws = (char*)d_ws;
  u16* xb  = (u16*)(ws);                       // 16,777,216 B
  u16* wqT = (u16*)(ws + 16777216);            //  6,291,456 B
  u16* woT = (u16*)(ws + 23068672);            //  2,097,152 B
  u16* Qn  = (u16*)(ws + 25165824);            // 16,777,216 B
  u16* Kn  = (u16*)(ws + 41943040);            // 16,777,216 B
  u16* Vt  = (u16*)(ws + 58720256);            // 16,777,216 B
  u16* hm  = (u16*)(ws + 75497472);            // 16,777,216 B  (end: 92,274,688)

  k_cvt_x<<<2048, 256, 0, stream>>>(x, xb);
  k_transpose<<<(1024 / 64) * (3072 / 64), 256, 0, stream>>>(Wqkv, wqT, 1024, 3072);
  k_transpose<<<(1024 / 64) * (1024 / 64), 256, 0, stream>>>(Wout, woT, 1024, 1024);
  k_gemm_qkv<<<(TOK / 128) * (C3 / 128), 256, 0, stream>>>(xb, wqT, bqkv, gq, gk, Qn, Kn, Vt);
  k_attn<<<BH * (SL / 128), 256, 0, stream>>>(Qn, Kn, Vt, hm);
  k_gemm_out<<<(TOK / 128) * (CIN / 128), 256, 0, stream>>>(hm, woT, bout, out);
}

// Round 3
// 228.513 us; speedup vs baseline: 1.6574x; 1.1199x over previous
//
#include <hip/hip_runtime.h>

using u16 = unsigned short;

typedef float  f32x4  __attribute__((ext_vector_type(4)));
typedef float  f32x16 __attribute__((ext_vector_type(16)));
typedef __bf16 bf16x8 __attribute__((ext_vector_type(8)));
typedef short  s16x8  __attribute__((ext_vector_type(8)));

#define DEVI __device__ __forceinline__

constexpr int TOK = 8192;    // N = B*L
constexpr int CIN = 1024;    // C
constexpr int C3  = 3072;    // 3C
constexpr int NH  = 16;
constexpr int HD  = 64;
constexpr int SL  = 2048;
constexpr int BH  = 64;      // B*H

constexpr float LOG2E = 1.4426950408889634f;

DEVI u16 f2bf(float x) {
  unsigned u = __builtin_bit_cast(unsigned, x);
  u += 0x7FFFu + ((u >> 16) & 1u);   // round-to-nearest-even
  return (u16)(u >> 16);
}

DEVI f32x4 mfma16(s16x8 a, s16x8 b, f32x4 c) {
  return __builtin_amdgcn_mfma_f32_16x16x32_bf16(
      __builtin_bit_cast(bf16x8, a), __builtin_bit_cast(bf16x8, b), c, 0, 0, 0);
}

DEVI f32x16 mfma32(s16x8 a, s16x8 b, f32x16 c) {
  return __builtin_amdgcn_mfma_f32_32x32x16_bf16(
      __builtin_bit_cast(bf16x8, a), __builtin_bit_cast(bf16x8, b), c, 0, 0, 0);
}

DEVI void gload_lds16(const void* g, void* l) {
  __builtin_amdgcn_global_load_lds(
      (const __attribute__((address_space(1))) unsigned int*)g,
      (__attribute__((address_space(3))) unsigned int*)l, 16, 0, 0);
}

DEVI unsigned cvtpk(float lo, float hi) {
  unsigned r;
  asm("v_cvt_pk_bf16_f32 %0, %1, %2" : "=v"(r) : "v"(lo), "v"(hi));
  return r;
}

DEVI void plswap(unsigned& a, unsigned& b) {
  asm("v_permlane32_swap_b32 %0, %1" : "+v"(a), "+v"(b));
}

// ---------------- convert x (fp32) -> bf16 ----------------
__global__ __launch_bounds__(256) void k_cvt_x(const float* __restrict__ x,
                                               u16* __restrict__ xb) {
  const int total = TOK * CIN / 4;
  for (int i = blockIdx.x * 256 + threadIdx.x; i < total; i += gridDim.x * 256) {
    float4 v = ((const float4*)x)[i];
    ushort4 o;
    o.x = f2bf(v.x); o.y = f2bf(v.y); o.z = f2bf(v.z); o.w = f2bf(v.w);
    ((ushort4*)xb)[i] = o;
  }
}

// ---------------- transpose fp32 [R][C] -> bf16 [C][R] ----------------
__global__ __launch_bounds__(256) void k_transpose(const float* __restrict__ in,
                                                   u16* __restrict__ out,
                                                   int R, int C) {
  __shared__ u16 t[64][72];
  int rt = R >> 6;
  int tr = (blockIdx.x % rt) << 6;
  int tc = (blockIdx.x / rt) << 6;
  int tid = threadIdx.x;
#pragma unroll
  for (int k2 = 0; k2 < 16; k2++) {
    int idx = k2 * 256 + tid;
    int r = idx >> 6, c = idx & 63;
    t[r][c] = f2bf(in[(size_t)(tr + r) * C + tc + c]);
  }
  __syncthreads();
#pragma unroll
  for (int k2 = 0; k2 < 16; k2++) {
    int idx = k2 * 256 + tid;
    int r = idx >> 6, c = idx & 63;
    out[(size_t)(tc + r) * R + tr + c] = t[c][r];
  }
}

// ---------------- GEMM1: qkv = xb @ wqkvT^T, fused bias+norm+repack ----------------
__global__ __launch_bounds__(256) void k_gemm_qkv(
    const u16* __restrict__ A, const u16* __restrict__ Bt,
    const float* __restrict__ bias, const float* __restrict__ gq,
    const float* __restrict__ gk,
    u16* __restrict__ Qn, u16* __restrict__ Kn, u16* __restrict__ Vt) {
  constexpr int BK = 32, K = 1024, NT = C3 / 128;
  __shared__ u16 As[128 * BK], Bs[128 * BK];
  const int bm = (blockIdx.x / NT) * 128, bn = (blockIdx.x % NT) * 128;
  const int tid = threadIdx.x, lane = tid & 63, w = tid >> 6;
  const int l15 = lane & 15, g = lane >> 4;
  const int wr = (w >> 1) * 64, wc = (w & 1) * 64;

  f32x4 acc[4][4];
#pragma unroll
  for (int i = 0; i < 4; i++)
#pragma unroll
    for (int j = 0; j < 4; j++) acc[i][j] = f32x4{0.f, 0.f, 0.f, 0.f};

  const int srow = tid >> 2, scol = (tid & 3) * 8;
  const u16* Ag = A + (size_t)(bm + srow) * K + scol;
  const u16* Bg = Bt + (size_t)(bn + srow) * K + scol;
  char* AsB = (char*)As;
  char* BsB = (char*)Bs;

  for (int k0 = 0; k0 < K; k0 += BK) {
    __syncthreads();
    gload_lds16(Ag + k0,          AsB + w * 1024);
    gload_lds16(Ag + 64 * K + k0, AsB + 4096 + w * 1024);
    gload_lds16(Bg + k0,          BsB + w * 1024);
    gload_lds16(Bg + 64 * K + k0, BsB + 4096 + w * 1024);
    __syncthreads();
    s16x8 af[4], bf[4];
#pragma unroll
    for (int mf = 0; mf < 4; mf++)
      af[mf] = *(const s16x8*)(As + (wr + mf * 16 + l15) * BK + g * 8);
#pragma unroll
    for (int nf = 0; nf < 4; nf++)
      bf[nf] = *(const s16x8*)(Bs + (wc + nf * 16 + l15) * BK + g * 8);
#pragma unroll
    for (int mf = 0; mf < 4; mf++)
#pragma unroll
      for (int nf = 0; nf < 4; nf++)
        acc[mf][nf] = mfma16(af[mf], bf[nf], acc[mf][nf]);
  }

  // epilogue: bias, per-head L2 norm for q/k (64 cols == one head), repack
  const int c0 = bn + wc;             // 64-aligned
  const int sec = c0 >> 10;           // 0=q 1=k 2=v
  const int head = (c0 & 1023) >> 6;
  float bv[4], gv[4];
#pragma unroll
  for (int nf = 0; nf < 4; nf++) {
    bv[nf] = bias[c0 + nf * 16 + l15];
    gv[nf] = 1.f;
    if (sec == 0) gv[nf] = gq[head * 64 + nf * 16 + l15];
    if (sec == 1) gv[nf] = gk[head * 64 + nf * 16 + l15];
  }
#pragma unroll
  for (int mf = 0; mf < 4; mf++) {
#pragma unroll
    for (int nf = 0; nf < 4; nf++)
#pragma unroll
      for (int r = 0; r < 4; r++) acc[mf][nf][r] += bv[nf];
    if (sec < 2) {
#pragma unroll
      for (int r = 0; r < 4; r++) {
        float ss = 0.f;
#pragma unroll
        for (int nf = 0; nf < 4; nf++) ss += acc[mf][nf][r] * acc[mf][nf][r];
        ss += __shfl_xor(ss, 1); ss += __shfl_xor(ss, 2);
        ss += __shfl_xor(ss, 4); ss += __shfl_xor(ss, 8);
        float nrm = fmaxf(sqrtf(ss), 1e-12f);
        float f = (sec == 0 ? LOG2E : 8.0f) / nrm;
#pragma unroll
        for (int nf = 0; nf < 4; nf++) acc[mf][nf][r] *= f;
      }
    }
    int rbase = bm + wr + mf * 16 + 4 * g;
#pragma unroll
    for (int r = 0; r < 4; r++) {
      int row = rbase + r;
      int b = row >> 11, tok = row & 2047;
      int bh = b * NH + head;
#pragma unroll
      for (int nf = 0; nf < 4; nf++) {
        int d = nf * 16 + l15;
        u16 val = f2bf(acc[mf][nf][r] * gv[nf]);
        if (sec == 0)      Qn[((size_t)bh * SL + tok) * HD + d] = val;
        else if (sec == 1) Kn[((size_t)bh * SL + tok) * HD + d] = val;
        else               Vt[((size_t)bh * HD + d) * SL + tok] = val;
      }
    }
  }
}

// ---------------- flash attention: 8 waves x 32 q = 256 q/block ----------------
// KVBLK=64 double-buffered in swizzled LDS (shared by all 8 waves).
// Swapped QK^T (lane = q column), in-register softmax, T12 P->bf16,
// T13 defer-rescale, treed reductions, T5 setprio.
__global__ __launch_bounds__(512) void k_attn(const u16* __restrict__ Qn,
                                              const u16* __restrict__ Kn,
                                              const u16* __restrict__ Vt,
                                              u16* __restrict__ hm) {
  __shared__ __align__(16) char KL[2][8192];
  __shared__ __align__(16) char VL[2][8192];
  const int bh = blockIdx.x & 63, qb = blockIdx.x >> 6;   // qb 0..7
  const int tid = threadIdx.x, w = tid >> 6, lane = tid & 63;
  const int l31 = lane & 31, h = lane >> 5;
  const int qr0 = qb * 256 + w * 32;

  // ---- staging source addresses (per thread), pre-swizzled ----
  const int sr  = tid >> 3;                                  // 0..63 rows
  const int scb = ((tid & 7) << 4) ^ ((sr & 7) << 4);        // swizzled col-byte
  const char* kst = (const char*)(Kn + (size_t)bh * SL * HD) + (size_t)sr * 128 + scb;
  const char* vst = (const char*)(Vt + (size_t)bh * HD * SL) + (size_t)sr * 4096 + scb;
  char* kl0 = KL[0] + (w << 10);
  char* vl0 = VL[0] + (w << 10);
  char* kl1 = KL[1] + (w << 10);
  char* vl1 = VL[1] + (w << 10);

  // ---- Q B-fragments (once): lane holds Q[qr0+l31][ks*16 + 8h + j] ----
  const u16* Qb = Qn + ((size_t)bh * SL + qr0 + l31) * HD + 8 * h;
  s16x8 qf[4];
#pragma unroll
  for (int ks = 0; ks < 4; ks++) qf[ks] = *(const s16x8*)(Qb + ks * 16);

  // lane LDS read base byte offset (within a 32-row half tile)
  const int lb = l31 * 128 + ((h << 4) ^ ((l31 & 7) << 4));

  f32x16 o0, o1;
#pragma unroll
  for (int i = 0; i < 16; i++) { o0[i] = 0.f; o1[i] = 0.f; }
  float mr = -1e30f, lr = 0.f;   // lr: this lane's half-row partial sum

  // prologue: stage kb=0 into buf 0
  gload_lds16(kst, kl0);
  gload_lds16(vst, vl0);
  __syncthreads();

  for (int it = 0; it < 32; ++it) {
    const char* KB = (it & 1) ? KL[1] : KL[0];
    const char* VB = (it & 1) ? VL[1] : VL[0];
    if (it < 31) {                                   // prefetch next tile
      const size_t ko = (size_t)(it + 1) << 13;      // 64 rows * 128 B
      const size_t vo = (size_t)(it + 1) << 7;       // 64 toks * 2 B
      gload_lds16(kst + ko, (it & 1) ? kl0 : kl1);
      gload_lds16(vst + vo, (it & 1) ? vl0 : vl1);
    }

    // ---- QK^T (swapped): S^T[k][q], lane = one q column ----
    f32x16 s0, s1;
#pragma unroll
    for (int i = 0; i < 16; i++) { s0[i] = 0.f; s1[i] = 0.f; }
    __builtin_amdgcn_s_setprio(1);
#pragma unroll
    for (int ks = 0; ks < 4; ks++) {
      const s16x8 ka  = *(const s16x8*)(KB + (lb ^ (ks << 5)));
      const s16x8 kb2 = *(const s16x8*)(KB + 4096 + (lb ^ (ks << 5)));
      s0 = mfma32(ka, qf[ks], s0);
      s1 = mfma32(kb2, qf[ks], s1);
    }
    __builtin_amdgcn_s_setprio(0);

    // ---- treed max over this lane's 32 scores ----
    float mx8[8];
#pragma unroll
    for (int i = 0; i < 8; i++)
      mx8[i] = fmaxf(fmaxf(s0[i], s0[i + 8]), fmaxf(s1[i], s1[i + 8]));
    float m0 = fmaxf(fmaxf(mx8[0], mx8[1]), fmaxf(mx8[2], mx8[3]));
    float m1 = fmaxf(fmaxf(mx8[4], mx8[5]), fmaxf(mx8[6], mx8[7]));
    float bm = fmaxf(m0, m1);
    bm = fmaxf(bm, __shfl_xor(bm, 32));   // cross-half: both halves same q

    // ---- T13 defer-rescale ----
    if (!__all(bm <= mr + 8.f)) {
      const float mn = fmaxf(mr, bm);
      const float sc = __builtin_amdgcn_exp2f(mr - mn);
      mr = mn;
      lr *= sc;
#pragma unroll
      for (int i = 0; i < 16; i++) { o0[i] *= sc; o1[i] *= sc; }
    }
#pragma unroll
    for (int i = 0; i < 16; i++) s0[i] = __builtin_amdgcn_exp2f(s0[i] - mr);
#pragma unroll
    for (int i = 0; i < 16; i++) s1[i] = __builtin_amdgcn_exp2f(s1[i] - mr);
    float sm8[8];
#pragma unroll
    for (int i = 0; i < 8; i++)
      sm8[i] = (s0[i] + s0[i + 8]) + (s1[i] + s1[i + 8]);
    lr += ((sm8[0] + sm8[1]) + (sm8[2] + sm8[3])) +
          ((sm8[4] + sm8[5]) + (sm8[6] + sm8[7]));

    // ---- P -> bf16 B-fragments (T12), PV ----
    union PBu { unsigned u[4]; s16x8 v; } pb;
#define MK_PB(SV, B)                              \
    {                                             \
      unsigned a0 = cvtpk(SV[B + 0], SV[B + 1]);  \
      unsigned c0 = cvtpk(SV[B + 4], SV[B + 5]);  \
      plswap(a0, c0);                             \
      unsigned a1 = cvtpk(SV[B + 2], SV[B + 3]);  \
      unsigned c1 = cvtpk(SV[B + 6], SV[B + 7]);  \
      plswap(a1, c1);                             \
      pb.u[0] = a0; pb.u[1] = a1; pb.u[2] = c0; pb.u[3] = c1; \
    }
#define PV_STEP(KS)                                            \
    {                                                          \
      const s16x8 va = *(const s16x8*)(VB + (lb ^ (KS << 5))); \
      const s16x8 vb = *(const s16x8*)(VB + 4096 + (lb ^ (KS << 5))); \
      __builtin_amdgcn_s_setprio(1);                           \
      o0 = mfma32(va, pb.v, o0);                               \
      o1 = mfma32(vb, pb.v, o1);                               \
      __builtin_amdgcn_s_setprio(0);                           \
    }
    MK_PB(s0, 0) PV_STEP(0)
    MK_PB(s0, 8) PV_STEP(1)
    MK_PB(s1, 0) PV_STEP(2)
    MK_PB(s1, 8) PV_STEP(3)
#undef MK_PB
#undef PV_STEP

    __syncthreads();   // drains vmcnt: next buffer staged; this buffer free
  }

  // ---- epilogue: combine half-row sums, normalize, store ----
  const float ltot = lr + __shfl_xor(lr, 32);
  const float inv = 1.f / ltot;
  const int bq = bh >> 4, hh = bh & 15;
  u16* hb = hm + ((size_t)bq * SL + qr0 + l31) * CIN + hh * HD;
#pragma unroll
  for (int rg = 0; rg < 4; rg++) {
    const int d0 = 8 * rg + 4 * h;
    unsigned lo = cvtpk(o0[4 * rg + 0] * inv, o0[4 * rg + 1] * inv);
    unsigned hi = cvtpk(o0[4 * rg + 2] * inv, o0[4 * rg + 3] * inv);
    *(unsigned long long*)(hb + d0) =
        (unsigned long long)lo | ((unsigned long long)hi << 32);
    unsigned lo1 = cvtpk(o1[4 * rg + 0] * inv, o1[4 * rg + 1] * inv);
    unsigned hi1 = cvtpk(o1[4 * rg + 2] * inv, o1[4 * rg + 3] * inv);
    *(unsigned long long*)(hb + 32 + d0) =
        (unsigned long long)lo1 | ((unsigned long long)hi1 << 32);
  }
}

// ---------------- GEMM2: out = hm @ woutT^T + b_out (fp32 out) ----------------
__global__ __launch_bounds__(256) void k_gemm_out(
    const u16* __restrict__ A, const u16* __restrict__ Bt,
    const float* __restrict__ bias, float* __restrict__ out) {
  constexpr int BK = 32, K = 1024, NT = CIN / 128;
  __shared__ u16 As[128 * BK], Bs[128 * BK];
  const int bm = (blockIdx.x / NT) * 128, bn = (blockIdx.x % NT) * 128;
  const int tid = threadIdx.x, lane = tid & 63, w = tid >> 6;
  const int l15 = lane & 15, g = lane >> 4;
  const int wr = (w >> 1) * 64, wc = (w & 1) * 64;

  f32x4 acc[4][4];
#pragma unroll
  for (int i = 0; i < 4; i++)
#pragma unroll
    for (int j = 0; j < 4; j++) acc[i][j] = f32x4{0.f, 0.f, 0.f, 0.f};

  const int srow = tid >> 2, scol = (tid & 3) * 8;
  const u16* Ag = A + (size_t)(bm + srow) * K + scol;
  const u16* Bg = Bt + (size_t)(bn + srow) * K + scol;
  char* AsB = (char*)As;
  char* BsB = (char*)Bs;

  for (int k0 = 0; k0 < K; k0 += BK) {
    __syncthreads();
    gload_lds16(Ag + k0,          AsB + w * 1024);
    gload_lds16(Ag + 64 * K + k0, AsB + 4096 + w * 1024);
    gload_lds16(Bg + k0,          BsB + w * 1024);
    gload_lds16(Bg + 64 * K + k0, BsB + 4096 + w * 1024);
    __syncthreads();
    s16x8 af[4], bf[4];
#pragma unroll
    for (int mf = 0; mf < 4; mf++)
      af[mf] = *(const s16x8*)(As + (wr + mf * 16 + l15) * BK + g * 8);
#pragma unroll
    for (int nf = 0; nf < 4; nf++)
      bf[nf] = *(const s16x8*)(Bs + (wc + nf * 16 + l15) * BK + g * 8);
#pragma unroll
    for (int mf = 0; mf < 4; mf++)
#pragma unroll
      for (int nf = 0; nf < 4; nf++)
        acc[mf][nf] = mfma16(af[mf], bf[nf], acc[mf][nf]);
  }

  float bv[4];
#pragma unroll
  for (int nf = 0; nf < 4; nf++) bv[nf] = bias[bn + wc + nf * 16 + l15];
#pragma unroll
  for (int mf = 0; mf < 4; mf++)
#pragma unroll
    for (int r = 0; r < 4; r++) {
      int row = bm + wr + mf * 16 + 4 * g + r;
#pragma unroll
      for (int nf = 0; nf < 4; nf++)
        out[(size_t)row * CIN + bn + wc + nf * 16 + l15] = acc[mf][nf][r] + bv[nf];
    }
}

extern "C" void kernel_launch(void* const* d_in, const int* in_sizes, int n_in,
                              void* d_out, int out_size, void* d_ws, size_t ws_size,
                              hipStream_t stream) {
  const float* x    = (const float*)d_in[0];
  const float* Wqkv = (const float*)d_in[1];
  const float* bqkv = (const float*)d_in[2];
  const float* gq   = (const float*)d_in[3];
  const float* gk   = (const float*)d_in[4];
  const float* Wout = (const float*)d_in[5];
  const float* bout = (const float*)d_in[6];
  float* out = (float*)d_out;

  char* ws = (char*)d_ws;
  u16* xb  = (u16*)(ws);                       // 16,777,216 B
  u16* wqT = (u16*)(ws + 16777216);            //  6,291,456 B
  u16* woT = (u16*)(ws + 23068672);            //  2,097,152 B
  u16* Qn  = (u16*)(ws + 25165824);            // 16,777,216 B
  u16* Kn  = (u16*)(ws + 41943040);            // 16,777,216 B
  u16* Vt  = (u16*)(ws + 58720256);            // 16,777,216 B
  u16* hm  = (u16*)(ws + 75497472);            // 16,777,216 B  (end: 92,274,688)

  k_cvt_x<<<2048, 256, 0, stream>>>(x, xb);
  k_transpose<<<(1024 / 64) * (3072 / 64), 256, 0, stream>>>(Wqkv, wqT, 1024, 3072);
  k_transpose<<<(1024 / 64) * (1024 / 64), 256, 0, stream>>>(Wout, woT, 1024, 1024);
  k_gemm_qkv<<<(TOK / 128) * (C3 / 128), 256, 0, stream>>>(xb, wqT, bqkv, gq, gk, Qn, Kn, Vt);
  k_attn<<<BH * (SL / 256), 512, 0, stream>>>(Qn, Kn, Vt, hm);
  k_gemm_out<<<(TOK / 128) * (CIN / 128), 256, 0, stream>>>(hm, woT, bout, out);
}